// Round 3
// baseline (533.471 us; speedup 1.0000x reference)
//
#include <hip/hip_runtime.h>
#include <stdint.h>

#define T_TOK 4096
#define H_DIM 1024
#define E_NUM 8
#define I_DIM 2048
#define CAP   9216   // max padded assignments
#define MAXTILES 72  // CAP/128

typedef float f32x4 __attribute__((ext_vector_type(4)));
typedef __bf16 bf16x8 __attribute__((ext_vector_type(8)));
typedef unsigned short u16x8 __attribute__((ext_vector_type(8)));
typedef unsigned short u16x4 __attribute__((ext_vector_type(4)));

__device__ __forceinline__ unsigned short f2bf(float f) {
    union { float f; unsigned int u; } v; v.f = f;
    unsigned int u = v.u;
    return (unsigned short)((u + 0x7fffu + ((u >> 16) & 1u)) >> 16);  // RNE
}
__device__ __forceinline__ float bf2f(unsigned short s) {
    union { unsigned int u; float f; } v; v.u = ((unsigned int)s) << 16; return v.f;
}

// async global->LDS, 16B per lane. LDS dest = wave-uniform base + lane*16.
__device__ __forceinline__ void async16(const unsigned short* g, unsigned short* l) {
    __builtin_amdgcn_global_load_lds(
        (const __attribute__((address_space(1))) unsigned int*)g,
        (__attribute__((address_space(3))) unsigned int*)l,
        16, 0, 0);
}

// ---------- router: wave per token, butterfly reduce; x -> bf16. NO atomics ----------
__global__ __launch_bounds__(256)
void router_kernel(const float* __restrict__ x, const float* __restrict__ Wr,
                   unsigned short* __restrict__ xb, int* __restrict__ topidx,
                   float* __restrict__ topw) {
    int wv = threadIdx.x >> 6, lane = threadIdx.x & 63;
    int t = blockIdx.x * 4 + wv;
    const float* xrow = x + (size_t)t * H_DIM + lane * 16;
    const float* wrow = Wr + (size_t)lane * 16 * E_NUM;
    float acc[E_NUM];
#pragma unroll
    for (int e = 0; e < E_NUM; e++) acc[e] = 0.f;
    unsigned short xo[16];
#pragma unroll
    for (int c = 0; c < 4; c++) {
        f32x4 xv = *(const f32x4*)(xrow + c * 4);
#pragma unroll
        for (int k = 0; k < 4; k++) {
            float v = xv[k];
            xo[c * 4 + k] = f2bf(v);
            const float* wr = wrow + (c * 4 + k) * E_NUM;
#pragma unroll
            for (int e = 0; e < E_NUM; e++) acc[e] += v * wr[e];
        }
    }
    unsigned short* xbp = xb + (size_t)t * H_DIM + lane * 16;
    *(u16x8*)xbp = *(u16x8*)xo;
    *(u16x8*)(xbp + 8) = *(u16x8*)(xo + 8);
#pragma unroll
    for (int m = 1; m < 64; m <<= 1) {
#pragma unroll
        for (int e = 0; e < E_NUM; e++) acc[e] += __shfl_xor(acc[e], m);
    }
    if (lane == 0) {
        float v0 = -1e30f; int i0 = 0;
#pragma unroll
        for (int e = 0; e < E_NUM; e++) { if (acc[e] > v0) { v0 = acc[e]; i0 = e; } }
        float v1 = -1e30f; int i1 = 0;
#pragma unroll
        for (int e = 0; e < E_NUM; e++) { if (e != i0 && acc[e] > v1) { v1 = acc[e]; i1 = e; } }
        float e1 = __expf(v1 - v0);
        float s = 1.f + e1;
        topidx[t * 2 + 0] = i0; topidx[t * 2 + 1] = i1;
        topw[t * 2 + 0] = 1.f / s; topw[t * 2 + 1] = e1 / s;
    }
}

// ---------- single block: histogram (register+shfl, no global atomics) + offsets
//            + XCD-interleaved tile map + pad fill ----------
__global__ __launch_bounds__(256)
void offsets_pad_kernel(const int* __restrict__ topidx, int* __restrict__ padded,
                        int* __restrict__ offs, int* __restrict__ tile_e,
                        int* __restrict__ tile_base, int* __restrict__ ntiles,
                        int* __restrict__ list_tok, float* __restrict__ list_w) {
    __shared__ int sc[E_NUM], sp[E_NUM], so[E_NUM + 1], snt;
    __shared__ int ste[MAXTILES], stb[MAXTILES];
    __shared__ int whist[4][E_NUM];
    int tid = threadIdx.x;
    int wv = tid >> 6, lane = tid & 63;
    int cnt[E_NUM];
#pragma unroll
    for (int e = 0; e < E_NUM; e++) cnt[e] = 0;
    for (int a = tid; a < T_TOK * 2; a += 256) {
        int e = topidx[a];
#pragma unroll
        for (int k = 0; k < E_NUM; k++) cnt[k] += (e == k) ? 1 : 0;
    }
#pragma unroll
    for (int m = 1; m < 64; m <<= 1)
#pragma unroll
        for (int e = 0; e < E_NUM; e++) cnt[e] += __shfl_xor(cnt[e], m);
    if (lane == 0) {
#pragma unroll
        for (int e = 0; e < E_NUM; e++) whist[wv][e] = cnt[e];
    }
    if (tid < MAXTILES) { ste[tid] = 0; stb[tid] = 0; }
    __syncthreads();
    if (tid == 0) {
        int off = 0, nt_e[E_NUM];
        for (int e = 0; e < E_NUM; e++) {
            sc[e] = whist[0][e] + whist[1][e] + whist[2][e] + whist[3][e];
            so[e] = off;
            int p = (sc[e] + 127) & ~127;
            sp[e] = p; nt_e[e] = p >> 7; off += p;
        }
        so[E_NUM] = off;
        int t2 = 0;
        // round-robin across experts: same-expert tiles ~8 apart -> same XCD
        for (int r = 0; r < MAXTILES; r++)
            for (int e = 0; e < E_NUM; e++)
                if (r < nt_e[e]) { ste[t2] = e; stb[t2] = so[e] + (r << 7); t2++; }
        snt = t2;
    }
    __syncthreads();
    if (tid < E_NUM) { padded[tid] = sp[tid]; offs[tid] = so[tid]; }
    if (tid == E_NUM) { offs[E_NUM] = so[E_NUM]; ntiles[0] = snt; }
    if (tid < MAXTILES) { tile_e[tid] = ste[tid]; tile_base[tid] = stb[tid]; }
#pragma unroll
    for (int e = 0; e < E_NUM; e++)
        for (int pos = sc[e] + tid; pos < sp[e]; pos += 256) {
            list_tok[so[e] + pos] = 0;
            list_w[so[e] + pos] = 0.f;
        }
}

// ---------- scatter: block-aggregated cursors (256 global atomics total, not 8192) ----------
__global__ __launch_bounds__(256)
void scatter_kernel(const int* __restrict__ topidx, const float* __restrict__ topw,
                    const int* __restrict__ offs, int* __restrict__ cursors,
                    int* __restrict__ list_tok, float* __restrict__ list_w,
                    int* __restrict__ slot_of) {
    __shared__ int lcnt[E_NUM], gbase[E_NUM];
    int tid = threadIdx.x;
    if (tid < E_NUM) lcnt[tid] = 0;
    __syncthreads();
    int a = blockIdx.x * 256 + tid;
    int e = topidx[a];
    int lpos = atomicAdd(&lcnt[e], 1);      // LDS atomic: cheap
    __syncthreads();
    if (tid < E_NUM) gbase[tid] = atomicAdd(&cursors[tid], lcnt[tid]);
    __syncthreads();
    int slot = offs[e] + gbase[e] + lpos;
    list_tok[slot] = a >> 1;
    list_w[slot]   = topw[a];
    slot_of[a]     = slot;
}

// ---------- fused transpose + fp32->bf16 for all three weight tensors ----------
__global__ __launch_bounds__(256)
void transpose_all(const float* __restrict__ Wg, const float* __restrict__ Wu,
                   const float* __restrict__ Wd, unsigned short* __restrict__ wgT,
                   unsigned short* __restrict__ wuT, unsigned short* __restrict__ wdT) {
    __shared__ float tile[64][69];
    int z = blockIdx.z, bx = blockIdx.x, by = blockIdx.y;
    const float* in; unsigned short* out;
    int R, C, c0, r0;
    size_t mat = (size_t)H_DIM * I_DIM;
    if (z < 16) {               // Wg/Wu: R=H=1024, C=I=2048
        int e = z & 7;
        in  = (z < 8 ? Wg : Wu) + (size_t)e * mat;
        out = (z < 8 ? wgT : wuT) + (size_t)e * mat;
        R = H_DIM; C = I_DIM;
        c0 = bx * 64; r0 = by * 64;
    } else {                    // Wd: R=I=2048, C=H=1024
        int e = z - 16;
        in  = Wd + (size_t)e * mat;
        out = wdT + (size_t)e * mat;
        R = I_DIM; C = H_DIM;
        c0 = by * 64; r0 = bx * 64;
    }
    int tid = threadIdx.x;
    int lc = (tid & 15) * 4, lr = tid >> 4;
#pragma unroll
    for (int j = 0; j < 64; j += 16) {
        f32x4 v = *(const f32x4*)(in + (size_t)(r0 + lr + j) * C + c0 + lc);
        tile[lr + j][lc + 0] = v[0]; tile[lr + j][lc + 1] = v[1];
        tile[lr + j][lc + 2] = v[2]; tile[lr + j][lc + 3] = v[3];
    }
    __syncthreads();
    int r8 = (tid & 7) * 8;
#pragma unroll
    for (int cc = 0; cc < 64; cc += 32) {
        int c = cc + (tid >> 3);
        u16x8 u;
#pragma unroll
        for (int j = 0; j < 8; j++) u[j] = f2bf(tile[r8 + j][c]);
        *(u16x8*)(out + (size_t)(c0 + c) * R + r0 + r8) = u;
    }
}

// ---------- fused gate/up GEMM + SwiGLU ----------
// BM=128 BN=64 BK=64; 4 waves, wave-tile 64m x 32n per GEMM; acc = 64 VGPRs.
// v3: B STREAMED FROM GLOBAL (L1/L2-resident panels) — only A is LDS-staged.
// LDS per block-K-step drops 96KB -> 48KB (stage 16 + ds_read 32) vs MFMA 621cy:
// the LDS port was the binding resource (round-0: 32% MfmaUtil, 0 conflicts,
// 14% HBM). B-frag 16B/lane loads: 4 quads of one row = one 64B line.
// LDS total 17.4KB; (256,3) keeps 3 blocks/CU (round-2 lesson: occupancy first).
__global__ __launch_bounds__(256, 3)
void gemm_gateup(const unsigned short* __restrict__ xb, const unsigned short* __restrict__ wgT,
                 const unsigned short* __restrict__ wuT, const int* __restrict__ list_tok,
                 const float* __restrict__ list_w,
                 const int* __restrict__ tile_e, const int* __restrict__ tile_base,
                 const int* __restrict__ ntiles, unsigned short* __restrict__ hbuf) {
    int tile = blockIdx.x;
    if (tile >= ntiles[0]) return;
    int e = tile_e[tile], base = tile_base[tile], nt = blockIdx.y;

    __shared__ unsigned short As[128 * 64];
    __shared__ int toks[128];
    __shared__ float wsh[128];

    int tid = threadIdx.x;
    if (tid < 128) { toks[tid] = list_tok[base + tid]; wsh[tid] = list_w[base + tid]; }
    __syncthreads();

    const unsigned short* wg = wgT + ((size_t)e * I_DIM + (size_t)nt * 64) * H_DIM;
    const unsigned short* wu = wuT + ((size_t)e * I_DIM + (size_t)nt * 64) * H_DIM;

    int wv = tid >> 6, lane = tid & 63;
    int sr = lane >> 3, sc = lane & 7, gc = sc ^ sr;

    const unsigned short* ag[4];
    int lbA[4];
#pragma unroll
    for (int i = 0; i < 4; i++) {
        int row = wv * 32 + i * 8 + sr;
        ag[i]  = xb + (size_t)toks[row] * H_DIM + gc * 8;
        lbA[i] = (wv * 32 + i * 8) * 64;
    }

    int wm = (wv >> 1) * 64, wn = (wv & 1) * 32;
    int l16 = lane & 15, quad = lane >> 4;

    // B fragment base: global row = nt*64 + wn + j*16 + l16, k-offset quad*8.
    // Equivalent elements to the old LDS-staged read (verified index algebra):
    // k = kb + ks*32 + quad*8 == kb + (ks*4+quad)*8.
    const unsigned short* bgp = wg + (size_t)(wn + l16) * H_DIM + quad * 8;
    const unsigned short* bup = wu + (size_t)(wn + l16) * H_DIM + quad * 8;

    f32x4 accg[4][2], accu[4][2];
    f32x4 z = {0.f, 0.f, 0.f, 0.f};
#pragma unroll
    for (int i = 0; i < 4; i++)
#pragma unroll
        for (int j = 0; j < 2; j++) { accg[i][j] = z; accu[i][j] = z; }

    for (int kb = 0; kb < H_DIM; kb += 64) {
#pragma unroll
        for (int i = 0; i < 4; i++) async16(ag[i] + kb, &As[lbA[i]]);
        // B fragments straight from L1/L2 (no LDS round-trip)
        bf16x8 bg4[2][2], bu4[2][2];
#pragma unroll
        for (int ks = 0; ks < 2; ks++)
#pragma unroll
            for (int j = 0; j < 2; j++) {
                bg4[ks][j] = *(const bf16x8*)(bgp + (size_t)(j * 16) * H_DIM + kb + ks * 32);
                bu4[ks][j] = *(const bf16x8*)(bup + (size_t)(j * 16) * H_DIM + kb + ks * 32);
            }
        __syncthreads();
#pragma unroll
        for (int ks = 0; ks < 2; ks++) {
            bf16x8 af[4];
#pragma unroll
            for (int i = 0; i < 4; i++) {
                int row = wm + i * 16 + l16;
                int pos = ((ks * 4 + quad) ^ (row & 7)) * 8;
                af[i] = *(const bf16x8*)(&As[row * 64 + pos]);
            }
#pragma unroll
            for (int i = 0; i < 4; i++)
#pragma unroll
                for (int j = 0; j < 2; j++) {
                    accg[i][j] = __builtin_amdgcn_mfma_f32_16x16x32_bf16(af[i], bg4[ks][j], accg[i][j], 0, 0, 0);
                    accu[i][j] = __builtin_amdgcn_mfma_f32_16x16x32_bf16(af[i], bu4[ks][j], accu[i][j], 0, 0, 0);
                }
        }
        __syncthreads();
    }
#pragma unroll
    for (int i = 0; i < 4; i++) {
#pragma unroll
        for (int r = 0; r < 4; r++) {
            int row = wm + i * 16 + quad * 4 + r;     // C/D: col=lane&15, row=quad*4+reg
            float wgt = wsh[row];
            size_t hb = (size_t)(base + row) * I_DIM + (size_t)nt * 64 + wn;
#pragma unroll
            for (int j = 0; j < 2; j++) {
                float g = accg[i][j][r];
                float u = accu[i][j][r];
                float sig = 1.f / (1.f + __expf(-g));
                hbuf[hb + j * 16 + l16] = f2bf(g * sig * u * wgt);
            }
        }
    }
}

// ---------- down GEMM: dbuf[slot] = h[slot] @ Wd, bf16 out ----------
// BM=128 BN=64 BK=64; B streamed from global, A LDS-staged. LDS 16KB,
// ~100 total regs -> (256,4): 4 blocks/CU, 16 waves.
__global__ __launch_bounds__(256, 4)
void gemm_down(const unsigned short* __restrict__ hbuf, const unsigned short* __restrict__ wdT,
               const int* __restrict__ tile_e, const int* __restrict__ tile_base,
               const int* __restrict__ ntiles, unsigned short* __restrict__ dbuf) {
    int tile = blockIdx.x;
    if (tile >= ntiles[0]) return;
    int e = tile_e[tile], base = tile_base[tile], nt = blockIdx.y;

    __shared__ unsigned short As[128 * 64];

    int tid = threadIdx.x;
    const unsigned short* wd = wdT + ((size_t)e * H_DIM + (size_t)nt * 64) * I_DIM;

    int wv = tid >> 6, lane = tid & 63;
    int sr = lane >> 3, sc = lane & 7, gc = sc ^ sr;

    const unsigned short* ag[4];
    int lbA[4];
#pragma unroll
    for (int i = 0; i < 4; i++) {
        int row = wv * 32 + i * 8 + sr;
        ag[i] = hbuf + (size_t)(base + row) * I_DIM + gc * 8;
        lbA[i] = (wv * 32 + i * 8) * 64;
    }

    int wm = (wv >> 1) * 64, wn = (wv & 1) * 32;
    int l16 = lane & 15, quad = lane >> 4;

    const unsigned short* bdp = wd + (size_t)(wn + l16) * I_DIM + quad * 8;

    f32x4 acc[4][2];
    f32x4 z = {0.f, 0.f, 0.f, 0.f};
#pragma unroll
    for (int i = 0; i < 4; i++)
#pragma unroll
        for (int j = 0; j < 2; j++) acc[i][j] = z;

    for (int kb = 0; kb < I_DIM; kb += 64) {
#pragma unroll
        for (int i = 0; i < 4; i++) async16(ag[i] + kb, &As[lbA[i]]);
        bf16x8 bd[2][2];
#pragma unroll
        for (int ks = 0; ks < 2; ks++)
#pragma unroll
            for (int j = 0; j < 2; j++)
                bd[ks][j] = *(const bf16x8*)(bdp + (size_t)(j * 16) * I_DIM + kb + ks * 32);
        __syncthreads();
#pragma unroll
        for (int ks = 0; ks < 2; ks++) {
            bf16x8 af[4];
#pragma unroll
            for (int i = 0; i < 4; i++) {
                int row = wm + i * 16 + l16;
                int pos = ((ks * 4 + quad) ^ (row & 7)) * 8;
                af[i] = *(const bf16x8*)(&As[row * 64 + pos]);
            }
#pragma unroll
            for (int i = 0; i < 4; i++)
#pragma unroll
                for (int j = 0; j < 2; j++)
                    acc[i][j] = __builtin_amdgcn_mfma_f32_16x16x32_bf16(af[i], bd[ks][j], acc[i][j], 0, 0, 0);
        }
        __syncthreads();
    }
#pragma unroll
    for (int i = 0; i < 4; i++) {
#pragma unroll
        for (int r = 0; r < 4; r++) {
            int row = wm + i * 16 + quad * 4 + r;
            unsigned short* orow = dbuf + (size_t)(base + row) * H_DIM + (size_t)nt * 64 + wn;
#pragma unroll
            for (int j = 0; j < 2; j++)
                orow[j * 16 + l16] = f2bf(acc[i][j][r]);
        }
    }
}

// ---------- combine: out[t] = dbuf[slot0] + dbuf[slot1] (bf16 in, fp32 out) ----------
__global__ __launch_bounds__(256)
void combine_kernel(const unsigned short* __restrict__ dbuf, const int* __restrict__ slot_of,
                    float* __restrict__ out) {
    int t = blockIdx.x;
    int s0 = slot_of[2 * t], s1 = slot_of[2 * t + 1];
    int i = threadIdx.x;   // 256 threads x 4 elems = 1024 = H_DIM
    u16x4 a = *(const u16x4*)(dbuf + (size_t)s0 * H_DIM + i * 4);
    u16x4 b = *(const u16x4*)(dbuf + (size_t)s1 * H_DIM + i * 4);
    f32x4 o;
#pragma unroll
    for (int k = 0; k < 4; k++) o[k] = bf2f(a[k]) + bf2f(b[k]);
    *(f32x4*)(out + (size_t)t * H_DIM + i * 4) = o;
}

extern "C" void kernel_launch(void* const* d_in, const int* in_sizes, int n_in,
                              void* d_out, int out_size, void* d_ws, size_t ws_size,
                              hipStream_t stream) {
    const float* x  = (const float*)d_in[0];
    const float* Wr = (const float*)d_in[1];
    const float* Wg = (const float*)d_in[2];
    const float* Wu = (const float*)d_in[3];
    const float* Wd = (const float*)d_in[4];
    float* out = (float*)d_out;
    char* ws = (char*)d_ws;

    size_t off = 0;
    unsigned short* xb   = (unsigned short*)(ws + off); off += (size_t)T_TOK * H_DIM * 2;
    unsigned short* wgT  = (unsigned short*)(ws + off); off += (size_t)E_NUM * H_DIM * I_DIM * 2;
    unsigned short* wuT  = (unsigned short*)(ws + off); off += (size_t)E_NUM * H_DIM * I_DIM * 2;
    unsigned short* wdT  = (unsigned short*)(ws + off); off += (size_t)E_NUM * H_DIM * I_DIM * 2;
    unsigned short* hbuf = (unsigned short*)(ws + off); off += (size_t)CAP * I_DIM * 2;
    unsigned short* dbuf = (unsigned short*)(ws + off); off += (size_t)CAP * H_DIM * 2;
    int*   topidx  = (int*)(ws + off);   off += (size_t)T_TOK * 2 * 4;
    float* topw    = (float*)(ws + off); off += (size_t)T_TOK * 2 * 4;
    int*   slot_of = (int*)(ws + off);   off += (size_t)T_TOK * 2 * 4;
    int*   meta    = (int*)(ws + off);   off += 1024;
    int*   cursors = meta + 8;      // 8
    int*   padded  = meta + 16;     // 8
    int*   offs    = meta + 24;     // 9
    int*   ntiles  = meta + 33;     // 1
    int*   tile_e  = meta + 64;     // 72
    int*   tile_b  = meta + 136;    // 72
    int*   list_tok = (int*)(ws + off);  off += (size_t)CAP * 4;
    float* list_w   = (float*)(ws + off); off += (size_t)CAP * 4;

    hipMemsetAsync(meta, 0, 64, stream);  // cursors

    router_kernel<<<T_TOK / 4, 256, 0, stream>>>(x, Wr, xb, topidx, topw);
    transpose_all<<<dim3(32, 16, 24), 256, 0, stream>>>(Wg, Wu, Wd, wgT, wuT, wdT);
    offsets_pad_kernel<<<1, 256, 0, stream>>>(topidx, padded, offs, tile_e, tile_b, ntiles, list_tok, list_w);
    scatter_kernel<<<(T_TOK * 2) / 256, 256, 0, stream>>>(topidx, topw, offs, cursors, list_tok, list_w, slot_of);
    gemm_gateup<<<dim3(MAXTILES, I_DIM / 64), 256, 0, stream>>>(xb, wgT, wuT, list_tok, list_w, tile_e, tile_b, ntiles, hbuf);
    gemm_down<<<dim3(MAXTILES, H_DIM / 64), 256, 0, stream>>>(hbuf, wdT, tile_e, tile_b, ntiles, dbuf);
    combine_kernel<<<T_TOK, 256, 0, stream>>>(dbuf, slot_of, out);
}

// Round 4
// 441.498 us; speedup vs baseline: 1.2083x; 1.2083x over previous
//
#include <hip/hip_runtime.h>
#include <stdint.h>

#define T_TOK 4096
#define H_DIM 1024
#define E_NUM 8
#define I_DIM 2048
#define CAP   9216   // max padded assignments
#define MAXTILES 72  // CAP/128

typedef float f32x4 __attribute__((ext_vector_type(4)));
typedef __bf16 bf16x8 __attribute__((ext_vector_type(8)));
typedef unsigned short u16x8 __attribute__((ext_vector_type(8)));
typedef unsigned short u16x4 __attribute__((ext_vector_type(4)));

__device__ __forceinline__ unsigned short f2bf(float f) {
    union { float f; unsigned int u; } v; v.f = f;
    unsigned int u = v.u;
    return (unsigned short)((u + 0x7fffu + ((u >> 16) & 1u)) >> 16);  // RNE
}
__device__ __forceinline__ float bf2f(unsigned short s) {
    union { unsigned int u; float f; } v; v.u = ((unsigned int)s) << 16; return v.f;
}

// async global->LDS, 16B per lane. LDS dest = wave-uniform base + lane*16.
__device__ __forceinline__ void async16(const unsigned short* g, unsigned short* l) {
    __builtin_amdgcn_global_load_lds(
        (const __attribute__((address_space(1))) unsigned int*)g,
        (__attribute__((address_space(3))) unsigned int*)l,
        16, 0, 0);
}

// ---------- router: wave per token, butterfly reduce; x -> bf16. NO atomics ----------
__global__ __launch_bounds__(256)
void router_kernel(const float* __restrict__ x, const float* __restrict__ Wr,
                   unsigned short* __restrict__ xb, int* __restrict__ topidx,
                   float* __restrict__ topw) {
    int wv = threadIdx.x >> 6, lane = threadIdx.x & 63;
    int t = blockIdx.x * 4 + wv;
    const float* xrow = x + (size_t)t * H_DIM + lane * 16;
    const float* wrow = Wr + (size_t)lane * 16 * E_NUM;
    float acc[E_NUM];
#pragma unroll
    for (int e = 0; e < E_NUM; e++) acc[e] = 0.f;
    unsigned short xo[16];
#pragma unroll
    for (int c = 0; c < 4; c++) {
        f32x4 xv = *(const f32x4*)(xrow + c * 4);
#pragma unroll
        for (int k = 0; k < 4; k++) {
            float v = xv[k];
            xo[c * 4 + k] = f2bf(v);
            const float* wr = wrow + (c * 4 + k) * E_NUM;
#pragma unroll
            for (int e = 0; e < E_NUM; e++) acc[e] += v * wr[e];
        }
    }
    unsigned short* xbp = xb + (size_t)t * H_DIM + lane * 16;
    *(u16x8*)xbp = *(u16x8*)xo;
    *(u16x8*)(xbp + 8) = *(u16x8*)(xo + 8);
#pragma unroll
    for (int m = 1; m < 64; m <<= 1) {
#pragma unroll
        for (int e = 0; e < E_NUM; e++) acc[e] += __shfl_xor(acc[e], m);
    }
    if (lane == 0) {
        float v0 = -1e30f; int i0 = 0;
#pragma unroll
        for (int e = 0; e < E_NUM; e++) { if (acc[e] > v0) { v0 = acc[e]; i0 = e; } }
        float v1 = -1e30f; int i1 = 0;
#pragma unroll
        for (int e = 0; e < E_NUM; e++) { if (e != i0 && acc[e] > v1) { v1 = acc[e]; i1 = e; } }
        float e1 = __expf(v1 - v0);
        float s = 1.f + e1;
        topidx[t * 2 + 0] = i0; topidx[t * 2 + 1] = i1;
        topw[t * 2 + 0] = 1.f / s; topw[t * 2 + 1] = e1 / s;
    }
}

// ---------- single block: histogram (register+shfl, no global atomics) + offsets
//            + XCD-interleaved tile map + pad fill ----------
__global__ __launch_bounds__(256)
void offsets_pad_kernel(const int* __restrict__ topidx, int* __restrict__ padded,
                        int* __restrict__ offs, int* __restrict__ tile_e,
                        int* __restrict__ tile_base, int* __restrict__ ntiles,
                        int* __restrict__ list_tok, float* __restrict__ list_w) {
    __shared__ int sc[E_NUM], sp[E_NUM], so[E_NUM + 1], snt;
    __shared__ int ste[MAXTILES], stb[MAXTILES];
    __shared__ int whist[4][E_NUM];
    int tid = threadIdx.x;
    int wv = tid >> 6, lane = tid & 63;
    int cnt[E_NUM];
#pragma unroll
    for (int e = 0; e < E_NUM; e++) cnt[e] = 0;
    for (int a = tid; a < T_TOK * 2; a += 256) {
        int e = topidx[a];
#pragma unroll
        for (int k = 0; k < E_NUM; k++) cnt[k] += (e == k) ? 1 : 0;
    }
#pragma unroll
    for (int m = 1; m < 64; m <<= 1)
#pragma unroll
        for (int e = 0; e < E_NUM; e++) cnt[e] += __shfl_xor(cnt[e], m);
    if (lane == 0) {
#pragma unroll
        for (int e = 0; e < E_NUM; e++) whist[wv][e] = cnt[e];
    }
    if (tid < MAXTILES) { ste[tid] = 0; stb[tid] = 0; }
    __syncthreads();
    if (tid == 0) {
        int off = 0, nt_e[E_NUM];
        for (int e = 0; e < E_NUM; e++) {
            sc[e] = whist[0][e] + whist[1][e] + whist[2][e] + whist[3][e];
            so[e] = off;
            int p = (sc[e] + 127) & ~127;
            sp[e] = p; nt_e[e] = p >> 7; off += p;
        }
        so[E_NUM] = off;
        int t2 = 0;
        // round-robin across experts: same-expert tiles ~8 apart -> same XCD
        for (int r = 0; r < MAXTILES; r++)
            for (int e = 0; e < E_NUM; e++)
                if (r < nt_e[e]) { ste[t2] = e; stb[t2] = so[e] + (r << 7); t2++; }
        snt = t2;
    }
    __syncthreads();
    if (tid < E_NUM) { padded[tid] = sp[tid]; offs[tid] = so[tid]; }
    if (tid == E_NUM) { offs[E_NUM] = so[E_NUM]; ntiles[0] = snt; }
    if (tid < MAXTILES) { tile_e[tid] = ste[tid]; tile_base[tid] = stb[tid]; }
#pragma unroll
    for (int e = 0; e < E_NUM; e++)
        for (int pos = sc[e] + tid; pos < sp[e]; pos += 256) {
            list_tok[so[e] + pos] = 0;
            list_w[so[e] + pos] = 0.f;
        }
}

// ---------- scatter: block-aggregated cursors (256 global atomics total, not 8192) ----------
__global__ __launch_bounds__(256)
void scatter_kernel(const int* __restrict__ topidx, const float* __restrict__ topw,
                    const int* __restrict__ offs, int* __restrict__ cursors,
                    int* __restrict__ list_tok, float* __restrict__ list_w,
                    int* __restrict__ slot_of) {
    __shared__ int lcnt[E_NUM], gbase[E_NUM];
    int tid = threadIdx.x;
    if (tid < E_NUM) lcnt[tid] = 0;
    __syncthreads();
    int a = blockIdx.x * 256 + tid;
    int e = topidx[a];
    int lpos = atomicAdd(&lcnt[e], 1);      // LDS atomic: cheap
    __syncthreads();
    if (tid < E_NUM) gbase[tid] = atomicAdd(&cursors[tid], lcnt[tid]);
    __syncthreads();
    int slot = offs[e] + gbase[e] + lpos;
    list_tok[slot] = a >> 1;
    list_w[slot]   = topw[a];
    slot_of[a]     = slot;
}

// ---------- fused transpose + fp32->bf16 for all three weight tensors ----------
__global__ __launch_bounds__(256)
void transpose_all(const float* __restrict__ Wg, const float* __restrict__ Wu,
                   const float* __restrict__ Wd, unsigned short* __restrict__ wgT,
                   unsigned short* __restrict__ wuT, unsigned short* __restrict__ wdT) {
    __shared__ float tile[64][69];
    int z = blockIdx.z, bx = blockIdx.x, by = blockIdx.y;
    const float* in; unsigned short* out;
    int R, C, c0, r0;
    size_t mat = (size_t)H_DIM * I_DIM;
    if (z < 16) {               // Wg/Wu: R=H=1024, C=I=2048
        int e = z & 7;
        in  = (z < 8 ? Wg : Wu) + (size_t)e * mat;
        out = (z < 8 ? wgT : wuT) + (size_t)e * mat;
        R = H_DIM; C = I_DIM;
        c0 = bx * 64; r0 = by * 64;
    } else {                    // Wd: R=I=2048, C=H=1024
        int e = z - 16;
        in  = Wd + (size_t)e * mat;
        out = wdT + (size_t)e * mat;
        R = I_DIM; C = H_DIM;
        c0 = by * 64; r0 = bx * 64;
    }
    int tid = threadIdx.x;
    int lc = (tid & 15) * 4, lr = tid >> 4;
#pragma unroll
    for (int j = 0; j < 64; j += 16) {
        f32x4 v = *(const f32x4*)(in + (size_t)(r0 + lr + j) * C + c0 + lc);
        tile[lr + j][lc + 0] = v[0]; tile[lr + j][lc + 1] = v[1];
        tile[lr + j][lc + 2] = v[2]; tile[lr + j][lc + 3] = v[3];
    }
    __syncthreads();
    int r8 = (tid & 7) * 8;
#pragma unroll
    for (int cc = 0; cc < 64; cc += 32) {
        int c = cc + (tid >> 3);
        u16x8 u;
#pragma unroll
        for (int j = 0; j < 8; j++) u[j] = f2bf(tile[r8 + j][c]);
        *(u16x8*)(out + (size_t)(c0 + c) * R + r0 + r8) = u;
    }
}

// ---------- fused gate/up GEMM + SwiGLU ----------
// v4: round-0 geometry (BM=128 BN=64 BK=64, 4 waves, 64x32 wave-tile/matrix)
// + T3/T4 pipeline: double-buffered LDS, STAGE(next) issued BEFORE compute(cur),
// raw s_barrier (no implicit vmcnt(0) drain like __syncthreads), counted
// s_waitcnt vmcnt(8) in main loop (8 loads/wave/K-step stay in flight across
// the barrier), vmcnt(0) only at the peeled last iteration.
// toks/wsh read direct from global (broadcast, L2-hit) to fit LDS = 64KB exact.
// 2 blocks/CU; the explicit pipeline replaces the lost 3rd-block overlap.
__global__ __launch_bounds__(256, 2)
void gemm_gateup(const unsigned short* __restrict__ xb, const unsigned short* __restrict__ wgT,
                 const unsigned short* __restrict__ wuT, const int* __restrict__ list_tok,
                 const float* __restrict__ list_w,
                 const int* __restrict__ tile_e, const int* __restrict__ tile_base,
                 const int* __restrict__ ntiles, unsigned short* __restrict__ hbuf) {
    int tile = blockIdx.x;
    if (tile >= ntiles[0]) return;
    int e = tile_e[tile], base = tile_base[tile], nt = blockIdx.y;

    __shared__ unsigned short As[2][128 * 64];
    __shared__ unsigned short Bgs[2][64 * 64];
    __shared__ unsigned short Bus[2][64 * 64];

    int tid = threadIdx.x;
    const unsigned short* wg = wgT + ((size_t)e * I_DIM + (size_t)nt * 64) * H_DIM;
    const unsigned short* wu = wuT + ((size_t)e * I_DIM + (size_t)nt * 64) * H_DIM;

    int wv = tid >> 6, lane = tid & 63;
    int sr = lane >> 3, sc = lane & 7, gc = sc ^ sr;

    const unsigned short* ag[4]; const unsigned short* bgg[2]; const unsigned short* bug[2];
    int lbA[4], lbB[2];
#pragma unroll
    for (int i = 0; i < 4; i++) {
        int row = wv * 32 + i * 8 + sr;
        ag[i]  = xb + (size_t)list_tok[base + row] * H_DIM + gc * 8;
        lbA[i] = (wv * 32 + i * 8) * 64;
    }
#pragma unroll
    for (int i = 0; i < 2; i++) {
        int row = wv * 16 + i * 8 + sr;
        bgg[i] = wg + (size_t)row * H_DIM + gc * 8;
        bug[i] = wu + (size_t)row * H_DIM + gc * 8;
        lbB[i] = (wv * 16 + i * 8) * 64;
    }

    f32x4 accg[4][2], accu[4][2];
    f32x4 z = {0.f, 0.f, 0.f, 0.f};
#pragma unroll
    for (int i = 0; i < 4; i++)
#pragma unroll
        for (int j = 0; j < 2; j++) { accg[i][j] = z; accu[i][j] = z; }

    int wm = (wv >> 1) * 64, wn = (wv & 1) * 32;
    int l16 = lane & 15, quad = lane >> 4;

#define STAGE_GU(b, kb) do {                                              \
    _Pragma("unroll")                                                     \
    for (int i_ = 0; i_ < 4; i_++) async16(ag[i_] + (kb), &As[b][lbA[i_]]); \
    _Pragma("unroll")                                                     \
    for (int i_ = 0; i_ < 2; i_++) {                                      \
        async16(bgg[i_] + (kb), &Bgs[b][lbB[i_]]);                        \
        async16(bug[i_] + (kb), &Bus[b][lbB[i_]]);                        \
    }                                                                     \
} while (0)

#define COMPUTE_GU(b) do {                                                \
    _Pragma("unroll")                                                     \
    for (int ks = 0; ks < 2; ks++) {                                      \
        bf16x8 af[4], bg4[2], bu4[2];                                     \
        _Pragma("unroll")                                                 \
        for (int i_ = 0; i_ < 4; i_++) {                                  \
            int row = wm + i_ * 16 + l16;                                 \
            int pos = ((ks * 4 + quad) ^ (row & 7)) * 8;                  \
            af[i_] = *(const bf16x8*)(&As[b][row * 64 + pos]);            \
        }                                                                 \
        _Pragma("unroll")                                                 \
        for (int j_ = 0; j_ < 2; j_++) {                                  \
            int row = wn + j_ * 16 + l16;                                 \
            int pos = ((ks * 4 + quad) ^ (row & 7)) * 8;                  \
            bg4[j_] = *(const bf16x8*)(&Bgs[b][row * 64 + pos]);          \
            bu4[j_] = *(const bf16x8*)(&Bus[b][row * 64 + pos]);          \
        }                                                                 \
        _Pragma("unroll")                                                 \
        for (int i_ = 0; i_ < 4; i_++)                                    \
            _Pragma("unroll")                                             \
            for (int j_ = 0; j_ < 2; j_++) {                              \
                accg[i_][j_] = __builtin_amdgcn_mfma_f32_16x16x32_bf16(af[i_], bg4[j_], accg[i_][j_], 0, 0, 0); \
                accu[i_][j_] = __builtin_amdgcn_mfma_f32_16x16x32_bf16(af[i_], bu4[j_], accu[i_][j_], 0, 0, 0); \
            }                                                             \
    }                                                                     \
} while (0)

    // prologue: stage K-tile 0 into buf 0
    STAGE_GU(0, 0);
    int cur = 0;
    for (int t = 0; t < (H_DIM / 64) - 1; t++) {
        STAGE_GU(cur ^ 1, (t + 1) * 64);                 // next tile: 8 loads in flight
        asm volatile("s_waitcnt vmcnt(8)" ::: "memory"); // wait only cur's 8
        __builtin_amdgcn_s_barrier();
        __builtin_amdgcn_sched_barrier(0);
        COMPUTE_GU(cur);
        __builtin_amdgcn_sched_barrier(0);
        __builtin_amdgcn_s_barrier();                    // buf[cur] free for t+1's stage
        cur ^= 1;
    }
    asm volatile("s_waitcnt vmcnt(0)" ::: "memory");     // drain last tile
    __builtin_amdgcn_s_barrier();
    __builtin_amdgcn_sched_barrier(0);
    COMPUTE_GU(cur);
#undef STAGE_GU
#undef COMPUTE_GU

#pragma unroll
    for (int i = 0; i < 4; i++) {
#pragma unroll
        for (int r = 0; r < 4; r++) {
            int row = wm + i * 16 + quad * 4 + r;     // C/D: col=lane&15, row=quad*4+reg
            float wgt = list_w[base + row];
            size_t hb = (size_t)(base + row) * I_DIM + (size_t)nt * 64 + wn;
#pragma unroll
            for (int j = 0; j < 2; j++) {
                float g = accg[i][j][r];
                float u = accu[i][j][r];
                float sig = 1.f / (1.f + __expf(-g));
                hbuf[hb + j * 16 + l16] = f2bf(g * sig * u * wgt);
            }
        }
    }
}

// ---------- down GEMM: dbuf[slot] = h[slot] @ Wd, bf16 out ----------
// v4: same T3/T4 pipeline; 6 loads/wave/K-step -> vmcnt(6). LDS 48KB, (256,3).
__global__ __launch_bounds__(256, 3)
void gemm_down(const unsigned short* __restrict__ hbuf, const unsigned short* __restrict__ wdT,
               const int* __restrict__ tile_e, const int* __restrict__ tile_base,
               const int* __restrict__ ntiles, unsigned short* __restrict__ dbuf) {
    int tile = blockIdx.x;
    if (tile >= ntiles[0]) return;
    int e = tile_e[tile], base = tile_base[tile], nt = blockIdx.y;

    __shared__ unsigned short As[2][128 * 64];
    __shared__ unsigned short Bs[2][64 * 64];

    int tid = threadIdx.x;
    const unsigned short* wd = wdT + ((size_t)e * H_DIM + (size_t)nt * 64) * I_DIM;

    int wv = tid >> 6, lane = tid & 63;
    int sr = lane >> 3, sc = lane & 7, gc = sc ^ sr;

    const unsigned short* ag[4]; const unsigned short* bg[2];
    int lbA[4], lbB[2];
#pragma unroll
    for (int i = 0; i < 4; i++) {
        int row = wv * 32 + i * 8 + sr;
        ag[i] = hbuf + (size_t)(base + row) * I_DIM + gc * 8;
        lbA[i] = (wv * 32 + i * 8) * 64;
    }
#pragma unroll
    for (int i = 0; i < 2; i++) {
        int row = wv * 16 + i * 8 + sr;
        bg[i] = wd + (size_t)row * I_DIM + gc * 8;
        lbB[i] = (wv * 16 + i * 8) * 64;
    }

    f32x4 acc[4][2];
    f32x4 z = {0.f, 0.f, 0.f, 0.f};
#pragma unroll
    for (int i = 0; i < 4; i++)
#pragma unroll
        for (int j = 0; j < 2; j++) acc[i][j] = z;

    int wm = (wv >> 1) * 64, wn = (wv & 1) * 32;
    int l16 = lane & 15, quad = lane >> 4;

#define STAGE_D(b, kb) do {                                               \
    _Pragma("unroll")                                                     \
    for (int i_ = 0; i_ < 4; i_++) async16(ag[i_] + (kb), &As[b][lbA[i_]]); \
    _Pragma("unroll")                                                     \
    for (int i_ = 0; i_ < 2; i_++) async16(bg[i_] + (kb), &Bs[b][lbB[i_]]); \
} while (0)

#define COMPUTE_D(b) do {                                                 \
    _Pragma("unroll")                                                     \
    for (int ks = 0; ks < 2; ks++) {                                      \
        bf16x8 af[4], bf4[2];                                             \
        _Pragma("unroll")                                                 \
        for (int i_ = 0; i_ < 4; i_++) {                                  \
            int row = wm + i_ * 16 + l16;                                 \
            int pos = ((ks * 4 + quad) ^ (row & 7)) * 8;                  \
            af[i_] = *(const bf16x8*)(&As[b][row * 64 + pos]);            \
        }                                                                 \
        _Pragma("unroll")                                                 \
        for (int j_ = 0; j_ < 2; j_++) {                                  \
            int row = wn + j_ * 16 + l16;                                 \
            int pos = ((ks * 4 + quad) ^ (row & 7)) * 8;                  \
            bf4[j_] = *(const bf16x8*)(&Bs[b][row * 64 + pos]);           \
        }                                                                 \
        _Pragma("unroll")                                                 \
        for (int i_ = 0; i_ < 4; i_++)                                    \
            _Pragma("unroll")                                             \
            for (int j_ = 0; j_ < 2; j_++)                                \
                acc[i_][j_] = __builtin_amdgcn_mfma_f32_16x16x32_bf16(af[i_], bf4[j_], acc[i_][j_], 0, 0, 0); \
    }                                                                     \
} while (0)

    STAGE_D(0, 0);
    int cur = 0;
    for (int t = 0; t < (I_DIM / 64) - 1; t++) {
        STAGE_D(cur ^ 1, (t + 1) * 64);
        asm volatile("s_waitcnt vmcnt(6)" ::: "memory");
        __builtin_amdgcn_s_barrier();
        __builtin_amdgcn_sched_barrier(0);
        COMPUTE_D(cur);
        __builtin_amdgcn_sched_barrier(0);
        __builtin_amdgcn_s_barrier();
        cur ^= 1;
    }
    asm volatile("s_waitcnt vmcnt(0)" ::: "memory");
    __builtin_amdgcn_s_barrier();
    __builtin_amdgcn_sched_barrier(0);
    COMPUTE_D(cur);
#undef STAGE_D
#undef COMPUTE_D

#pragma unroll
    for (int i = 0; i < 4; i++) {
#pragma unroll
        for (int r = 0; r < 4; r++) {
            int row = wm + i * 16 + quad * 4 + r;
            unsigned short* orow = dbuf + (size_t)(base + row) * H_DIM + (size_t)nt * 64 + wn;
#pragma unroll
            for (int j = 0; j < 2; j++)
                orow[j * 16 + l16] = f2bf(acc[i][j][r]);
        }
    }
}

// ---------- combine: out[t] = dbuf[slot0] + dbuf[slot1] (bf16 in, fp32 out) ----------
__global__ __launch_bounds__(256)
void combine_kernel(const unsigned short* __restrict__ dbuf, const int* __restrict__ slot_of,
                    float* __restrict__ out) {
    int t = blockIdx.x;
    int s0 = slot_of[2 * t], s1 = slot_of[2 * t + 1];
    int i = threadIdx.x;   // 256 threads x 4 elems = 1024 = H_DIM
    u16x4 a = *(const u16x4*)(dbuf + (size_t)s0 * H_DIM + i * 4);
    u16x4 b = *(const u16x4*)(dbuf + (size_t)s1 * H_DIM + i * 4);
    f32x4 o;
#pragma unroll
    for (int k = 0; k < 4; k++) o[k] = bf2f(a[k]) + bf2f(b[k]);
    *(f32x4*)(out + (size_t)t * H_DIM + i * 4) = o;
}

extern "C" void kernel_launch(void* const* d_in, const int* in_sizes, int n_in,
                              void* d_out, int out_size, void* d_ws, size_t ws_size,
                              hipStream_t stream) {
    const float* x  = (const float*)d_in[0];
    const float* Wr = (const float*)d_in[1];
    const float* Wg = (const float*)d_in[2];
    const float* Wu = (const float*)d_in[3];
    const float* Wd = (const float*)d_in[4];
    float* out = (float*)d_out;
    char* ws = (char*)d_ws;

    size_t off = 0;
    unsigned short* xb   = (unsigned short*)(ws + off); off += (size_t)T_TOK * H_DIM * 2;
    unsigned short* wgT  = (unsigned short*)(ws + off); off += (size_t)E_NUM * H_DIM * I_DIM * 2;
    unsigned short* wuT  = (unsigned short*)(ws + off); off += (size_t)E_NUM * H_DIM * I_DIM * 2;
    unsigned short* wdT  = (unsigned short*)(ws + off); off += (size_t)E_NUM * H_DIM * I_DIM * 2;
    unsigned short* hbuf = (unsigned short*)(ws + off); off += (size_t)CAP * I_DIM * 2;
    unsigned short* dbuf = (unsigned short*)(ws + off); off += (size_t)CAP * H_DIM * 2;
    int*   topidx  = (int*)(ws + off);   off += (size_t)T_TOK * 2 * 4;
    float* topw    = (float*)(ws + off); off += (size_t)T_TOK * 2 * 4;
    int*   slot_of = (int*)(ws + off);   off += (size_t)T_TOK * 2 * 4;
    int*   meta    = (int*)(ws + off);   off += 1024;
    int*   cursors = meta + 8;      // 8
    int*   padded  = meta + 16;     // 8
    int*   offs    = meta + 24;     // 9
    int*   ntiles  = meta + 33;     // 1
    int*   tile_e  = meta + 64;     // 72
    int*   tile_b  = meta + 136;    // 72
    int*   list_tok = (int*)(ws + off);  off += (size_t)CAP * 4;
    float* list_w   = (float*)(ws + off); off += (size_t)CAP * 4;

    hipMemsetAsync(meta, 0, 64, stream);  // cursors

    router_kernel<<<T_TOK / 4, 256, 0, stream>>>(x, Wr, xb, topidx, topw);
    transpose_all<<<dim3(32, 16, 24), 256, 0, stream>>>(Wg, Wu, Wd, wgT, wuT, wdT);
    offsets_pad_kernel<<<1, 256, 0, stream>>>(topidx, padded, offs, tile_e, tile_b, ntiles, list_tok, list_w);
    scatter_kernel<<<(T_TOK * 2) / 256, 256, 0, stream>>>(topidx, topw, offs, cursors, list_tok, list_w, slot_of);
    gemm_gateup<<<dim3(MAXTILES, I_DIM / 64), 256, 0, stream>>>(xb, wgT, wuT, list_tok, list_w, tile_e, tile_b, ntiles, hbuf);
    gemm_down<<<dim3(MAXTILES, H_DIM / 64), 256, 0, stream>>>(hbuf, wdT, tile_e, tile_b, ntiles, dbuf);
    combine_kernel<<<T_TOK, 256, 0, stream>>>(dbuf, slot_of, out);
}

// Round 5
// 416.359 us; speedup vs baseline: 1.2813x; 1.0604x over previous
//
#include <hip/hip_runtime.h>
#include <stdint.h>

#define T_TOK 4096
#define H_DIM 1024
#define E_NUM 8
#define I_DIM 2048
#define CAP   9216   // max padded assignments
#define MAXTILES 72  // CAP/128

typedef float f32x4 __attribute__((ext_vector_type(4)));
typedef __bf16 bf16x8 __attribute__((ext_vector_type(8)));
typedef unsigned short u16x8 __attribute__((ext_vector_type(8)));
typedef unsigned short u16x4 __attribute__((ext_vector_type(4)));

__device__ __forceinline__ unsigned short f2bf(float f) {
    union { float f; unsigned int u; } v; v.f = f;
    unsigned int u = v.u;
    return (unsigned short)((u + 0x7fffu + ((u >> 16) & 1u)) >> 16);  // RNE
}
__device__ __forceinline__ float bf2f(unsigned short s) {
    union { unsigned int u; float f; } v; v.u = ((unsigned int)s) << 16; return v.f;
}

// async global->LDS, 16B per lane. LDS dest = wave-uniform base + lane*16.
__device__ __forceinline__ void async16(const unsigned short* g, unsigned short* l) {
    __builtin_amdgcn_global_load_lds(
        (const __attribute__((address_space(1))) unsigned int*)g,
        (__attribute__((address_space(3))) unsigned int*)l,
        16, 0, 0);
}

// ---------- router: wave per token, butterfly reduce; x -> bf16. NO atomics ----------
__global__ __launch_bounds__(256)
void router_kernel(const float* __restrict__ x, const float* __restrict__ Wr,
                   unsigned short* __restrict__ xb, int* __restrict__ topidx,
                   float* __restrict__ topw) {
    int wv = threadIdx.x >> 6, lane = threadIdx.x & 63;
    int t = blockIdx.x * 4 + wv;
    const float* xrow = x + (size_t)t * H_DIM + lane * 16;
    const float* wrow = Wr + (size_t)lane * 16 * E_NUM;
    float acc[E_NUM];
#pragma unroll
    for (int e = 0; e < E_NUM; e++) acc[e] = 0.f;
    unsigned short xo[16];
#pragma unroll
    for (int c = 0; c < 4; c++) {
        f32x4 xv = *(const f32x4*)(xrow + c * 4);
#pragma unroll
        for (int k = 0; k < 4; k++) {
            float v = xv[k];
            xo[c * 4 + k] = f2bf(v);
            const float* wr = wrow + (c * 4 + k) * E_NUM;
#pragma unroll
            for (int e = 0; e < E_NUM; e++) acc[e] += v * wr[e];
        }
    }
    unsigned short* xbp = xb + (size_t)t * H_DIM + lane * 16;
    *(u16x8*)xbp = *(u16x8*)xo;
    *(u16x8*)(xbp + 8) = *(u16x8*)(xo + 8);
#pragma unroll
    for (int m = 1; m < 64; m <<= 1) {
#pragma unroll
        for (int e = 0; e < E_NUM; e++) acc[e] += __shfl_xor(acc[e], m);
    }
    if (lane == 0) {
        float v0 = -1e30f; int i0 = 0;
#pragma unroll
        for (int e = 0; e < E_NUM; e++) { if (acc[e] > v0) { v0 = acc[e]; i0 = e; } }
        float v1 = -1e30f; int i1 = 0;
#pragma unroll
        for (int e = 0; e < E_NUM; e++) { if (e != i0 && acc[e] > v1) { v1 = acc[e]; i1 = e; } }
        float e1 = __expf(v1 - v0);
        float s = 1.f + e1;
        topidx[t * 2 + 0] = i0; topidx[t * 2 + 1] = i1;
        topw[t * 2 + 0] = 1.f / s; topw[t * 2 + 1] = e1 / s;
    }
}

// ---------- single block: histogram + offsets + XCD-interleaved tile map
//            + scatter (LDS cursors, no global atomics) + pad fill.
//            Merges the old offsets_pad + scatter kernels; removes the memset. ----------
__global__ __launch_bounds__(256)
void offsets_scatter_kernel(const int* __restrict__ topidx, const float* __restrict__ topw,
                            int* __restrict__ tile_e, int* __restrict__ tile_base,
                            int* __restrict__ ntiles,
                            int* __restrict__ list_tok, float* __restrict__ list_w,
                            int* __restrict__ slot_of) {
    __shared__ int sc[E_NUM], sp[E_NUM], so[E_NUM + 1], snt;
    __shared__ int ste[MAXTILES], stb[MAXTILES];
    __shared__ int whist[4][E_NUM];
    __shared__ int scur[E_NUM];
    int tid = threadIdx.x;
    int wv = tid >> 6, lane = tid & 63;
    int cnt[E_NUM];
#pragma unroll
    for (int e = 0; e < E_NUM; e++) cnt[e] = 0;
    for (int a = tid; a < T_TOK * 2; a += 256) {
        int e = topidx[a];
#pragma unroll
        for (int k = 0; k < E_NUM; k++) cnt[k] += (e == k) ? 1 : 0;
    }
#pragma unroll
    for (int m = 1; m < 64; m <<= 1)
#pragma unroll
        for (int e = 0; e < E_NUM; e++) cnt[e] += __shfl_xor(cnt[e], m);
    if (lane == 0) {
#pragma unroll
        for (int e = 0; e < E_NUM; e++) whist[wv][e] = cnt[e];
    }
    if (tid < E_NUM) scur[tid] = 0;
    if (tid < MAXTILES) { ste[tid] = 0; stb[tid] = 0; }
    __syncthreads();
    if (tid == 0) {
        int off = 0, nt_e[E_NUM];
        for (int e = 0; e < E_NUM; e++) {
            sc[e] = whist[0][e] + whist[1][e] + whist[2][e] + whist[3][e];
            so[e] = off;
            int p = (sc[e] + 127) & ~127;
            sp[e] = p; nt_e[e] = p >> 7; off += p;
        }
        so[E_NUM] = off;
        int t2 = 0;
        // round-robin across experts: same-expert tiles 8 apart -> same XCD
        for (int r = 0; r < MAXTILES; r++)
            for (int e = 0; e < E_NUM; e++)
                if (r < nt_e[e]) { ste[t2] = e; stb[t2] = so[e] + (r << 7); t2++; }
        snt = t2;
    }
    __syncthreads();
    if (tid == 0) ntiles[0] = snt;
    if (tid < MAXTILES) { tile_e[tid] = ste[tid]; tile_base[tid] = stb[tid]; }
    // scatter via LDS cursors (order within an expert is irrelevant to the math)
    for (int a = tid; a < T_TOK * 2; a += 256) {
        int e = topidx[a];
        int pos = atomicAdd(&scur[e], 1);
        int slot = so[e] + pos;
        list_tok[slot] = a >> 1;
        list_w[slot]   = topw[a];
        slot_of[a]     = slot;
    }
    // pad fill: [so[e]+sc[e], so[e]+sp[e]) is disjoint from scattered slots
#pragma unroll
    for (int e = 0; e < E_NUM; e++)
        for (int pos = sc[e] + tid; pos < sp[e]; pos += 256) {
            list_tok[so[e] + pos] = 0;
            list_w[so[e] + pos] = 0.f;
        }
}

// ---------- fused transpose + fp32->bf16 for all three weight tensors ----------
__global__ __launch_bounds__(256)
void transpose_all(const float* __restrict__ Wg, const float* __restrict__ Wu,
                   const float* __restrict__ Wd, unsigned short* __restrict__ wgT,
                   unsigned short* __restrict__ wuT, unsigned short* __restrict__ wdT) {
    __shared__ float tile[64][69];
    int z = blockIdx.z, bx = blockIdx.x, by = blockIdx.y;
    const float* in; unsigned short* out;
    int R, C, c0, r0;
    size_t mat = (size_t)H_DIM * I_DIM;
    if (z < 16) {               // Wg/Wu: R=H=1024, C=I=2048
        int e = z & 7;
        in  = (z < 8 ? Wg : Wu) + (size_t)e * mat;
        out = (z < 8 ? wgT : wuT) + (size_t)e * mat;
        R = H_DIM; C = I_DIM;
        c0 = bx * 64; r0 = by * 64;
    } else {                    // Wd: R=I=2048, C=H=1024
        int e = z - 16;
        in  = Wd + (size_t)e * mat;
        out = wdT + (size_t)e * mat;
        R = I_DIM; C = H_DIM;
        c0 = by * 64; r0 = bx * 64;
    }
    int tid = threadIdx.x;
    int lc = (tid & 15) * 4, lr = tid >> 4;
#pragma unroll
    for (int j = 0; j < 64; j += 16) {
        f32x4 v = *(const f32x4*)(in + (size_t)(r0 + lr + j) * C + c0 + lc);
        tile[lr + j][lc + 0] = v[0]; tile[lr + j][lc + 1] = v[1];
        tile[lr + j][lc + 2] = v[2]; tile[lr + j][lc + 3] = v[3];
    }
    __syncthreads();
    int r8 = (tid & 7) * 8;
#pragma unroll
    for (int cc = 0; cc < 64; cc += 32) {
        int c = cc + (tid >> 3);
        u16x8 u;
#pragma unroll
        for (int j = 0; j < 8; j++) u[j] = f2bf(tile[r8 + j][c]);
        *(u16x8*)(out + (size_t)(c0 + c) * R + r0 + r8) = u;
    }
}

// ---------- fused gate/up GEMM + SwiGLU (round-0 proven structure) ----------
// BM=128 BN=64 BK=64; 4 waves, wave-tile 64m x 32n per GEMM; acc = 64 VGPRs.
// (256,3): 3 blocks/CU. LDS unpadded (128B stride) for global_load_lds; XOR swizzle.
__global__ __launch_bounds__(256, 3)
void gemm_gateup(const unsigned short* __restrict__ xb, const unsigned short* __restrict__ wgT,
                 const unsigned short* __restrict__ wuT, const int* __restrict__ list_tok,
                 const float* __restrict__ list_w,
                 const int* __restrict__ tile_e, const int* __restrict__ tile_base,
                 const int* __restrict__ ntiles, unsigned short* __restrict__ hbuf) {
    int tile = blockIdx.x;
    if (tile >= ntiles[0]) return;
    int e = tile_e[tile], base = tile_base[tile], nt = blockIdx.y;

    __shared__ unsigned short As[128 * 64];
    __shared__ unsigned short Bgs[64 * 64];
    __shared__ unsigned short Bus[64 * 64];
    __shared__ int toks[128];
    __shared__ float wsh[128];

    int tid = threadIdx.x;
    if (tid < 128) { toks[tid] = list_tok[base + tid]; wsh[tid] = list_w[base + tid]; }
    __syncthreads();

    const unsigned short* wg = wgT + ((size_t)e * I_DIM + (size_t)nt * 64) * H_DIM;
    const unsigned short* wu = wuT + ((size_t)e * I_DIM + (size_t)nt * 64) * H_DIM;

    int wv = tid >> 6, lane = tid & 63;
    int sr = lane >> 3, sc = lane & 7, gc = sc ^ sr;

    const unsigned short* ag[4]; const unsigned short* bgg[2]; const unsigned short* bug[2];
    int lbA[4], lbB[2];
#pragma unroll
    for (int i = 0; i < 4; i++) {
        int row = wv * 32 + i * 8 + sr;
        ag[i]  = xb + (size_t)toks[row] * H_DIM + gc * 8;
        lbA[i] = (wv * 32 + i * 8) * 64;
    }
#pragma unroll
    for (int i = 0; i < 2; i++) {
        int row = wv * 16 + i * 8 + sr;
        bgg[i] = wg + (size_t)row * H_DIM + gc * 8;
        bug[i] = wu + (size_t)row * H_DIM + gc * 8;
        lbB[i] = (wv * 16 + i * 8) * 64;
    }

    f32x4 accg[4][2], accu[4][2];
    f32x4 z = {0.f, 0.f, 0.f, 0.f};
#pragma unroll
    for (int i = 0; i < 4; i++)
#pragma unroll
        for (int j = 0; j < 2; j++) { accg[i][j] = z; accu[i][j] = z; }

    int wm = (wv >> 1) * 64, wn = (wv & 1) * 32;
    int l16 = lane & 15, quad = lane >> 4;

    for (int kb = 0; kb < H_DIM; kb += 64) {
#pragma unroll
        for (int i = 0; i < 4; i++) async16(ag[i] + kb, &As[lbA[i]]);
#pragma unroll
        for (int i = 0; i < 2; i++) {
            async16(bgg[i] + kb, &Bgs[lbB[i]]);
            async16(bug[i] + kb, &Bus[lbB[i]]);
        }
        __syncthreads();
#pragma unroll
        for (int ks = 0; ks < 2; ks++) {
            bf16x8 af[4], bg4[2], bu4[2];
#pragma unroll
            for (int i = 0; i < 4; i++) {
                int row = wm + i * 16 + l16;
                int pos = ((ks * 4 + quad) ^ (row & 7)) * 8;
                af[i] = *(const bf16x8*)(&As[row * 64 + pos]);
            }
#pragma unroll
            for (int j = 0; j < 2; j++) {
                int row = wn + j * 16 + l16;
                int pos = ((ks * 4 + quad) ^ (row & 7)) * 8;
                bg4[j] = *(const bf16x8*)(&Bgs[row * 64 + pos]);
                bu4[j] = *(const bf16x8*)(&Bus[row * 64 + pos]);
            }
#pragma unroll
            for (int i = 0; i < 4; i++)
#pragma unroll
                for (int j = 0; j < 2; j++) {
                    accg[i][j] = __builtin_amdgcn_mfma_f32_16x16x32_bf16(af[i], bg4[j], accg[i][j], 0, 0, 0);
                    accu[i][j] = __builtin_amdgcn_mfma_f32_16x16x32_bf16(af[i], bu4[j], accu[i][j], 0, 0, 0);
                }
        }
        __syncthreads();
    }
#pragma unroll
    for (int i = 0; i < 4; i++) {
#pragma unroll
        for (int r = 0; r < 4; r++) {
            int row = wm + i * 16 + quad * 4 + r;     // C/D: col=lane&15, row=quad*4+reg
            float wgt = wsh[row];
            size_t hb = (size_t)(base + row) * I_DIM + (size_t)nt * 64 + wn;
#pragma unroll
            for (int j = 0; j < 2; j++) {
                float g = accg[i][j][r];
                float u = accu[i][j][r];
                float sig = 1.f / (1.f + __expf(-g));
                hbuf[hb + j * 16 + l16] = f2bf(g * sig * u * wgt);
            }
        }
    }
}

// ---------- down GEMM: dbuf[slot] = h[slot] @ Wd, bf16 out ----------
// v5: BM=128 BN=128 BK=64, 4 waves 2x2, wave-tile 64x64, acc[4][4]=64 VGPR.
// Single output matrix so (unlike round-2's gateup) regs fit at (256,3) with
// LDS 32KB. LDS traffic per MFMA drops 33% vs BN=64 (down was the worst
// FLOP/LDS-byte kernel). Grid 72x8=576 blocks: all co-resident (~2.25/CU),
// nt-blocks of a tile stay on one XCD (72%8==0) so hbuf re-reads are L2-local.
__global__ __launch_bounds__(256, 3)
void gemm_down(const unsigned short* __restrict__ hbuf, const unsigned short* __restrict__ wdT,
               const int* __restrict__ tile_e, const int* __restrict__ tile_base,
               const int* __restrict__ ntiles, unsigned short* __restrict__ dbuf) {
    int tile = blockIdx.x;
    if (tile >= ntiles[0]) return;
    int e = tile_e[tile], base = tile_base[tile], nt = blockIdx.y;  // nt: H/128

    __shared__ unsigned short As[128 * 64];
    __shared__ unsigned short Bs[128 * 64];

    int tid = threadIdx.x;
    const unsigned short* wd = wdT + ((size_t)e * H_DIM + (size_t)nt * 128) * I_DIM;

    int wv = tid >> 6, lane = tid & 63;
    int sr = lane >> 3, sc = lane & 7, gc = sc ^ sr;

    const unsigned short* ag[4]; const unsigned short* bg[4];
    int lb[4];
#pragma unroll
    for (int i = 0; i < 4; i++) {
        int row = wv * 32 + i * 8 + sr;
        ag[i] = hbuf + (size_t)(base + row) * I_DIM + gc * 8;
        bg[i] = wd + (size_t)row * I_DIM + gc * 8;
        lb[i] = (wv * 32 + i * 8) * 64;
    }

    f32x4 acc[4][4];
    f32x4 z = {0.f, 0.f, 0.f, 0.f};
#pragma unroll
    for (int i = 0; i < 4; i++)
#pragma unroll
        for (int j = 0; j < 4; j++) acc[i][j] = z;

    int wm = (wv >> 1) * 64, wn = (wv & 1) * 64;
    int l16 = lane & 15, quad = lane >> 4;

    for (int kb = 0; kb < I_DIM; kb += 64) {
#pragma unroll
        for (int i = 0; i < 4; i++) {
            async16(ag[i] + kb, &As[lb[i]]);
            async16(bg[i] + kb, &Bs[lb[i]]);
        }
        __syncthreads();
#pragma unroll
        for (int ks = 0; ks < 2; ks++) {
            bf16x8 af[4], bf4[4];
#pragma unroll
            for (int i = 0; i < 4; i++) {
                int row = wm + i * 16 + l16;
                int pos = ((ks * 4 + quad) ^ (row & 7)) * 8;
                af[i] = *(const bf16x8*)(&As[row * 64 + pos]);
            }
#pragma unroll
            for (int j = 0; j < 4; j++) {
                int row = wn + j * 16 + l16;
                int pos = ((ks * 4 + quad) ^ (row & 7)) * 8;
                bf4[j] = *(const bf16x8*)(&Bs[row * 64 + pos]);
            }
#pragma unroll
            for (int i = 0; i < 4; i++)
#pragma unroll
                for (int j = 0; j < 4; j++)
                    acc[i][j] = __builtin_amdgcn_mfma_f32_16x16x32_bf16(af[i], bf4[j], acc[i][j], 0, 0, 0);
        }
        __syncthreads();
    }
#pragma unroll
    for (int i = 0; i < 4; i++) {
#pragma unroll
        for (int r = 0; r < 4; r++) {
            int row = wm + i * 16 + quad * 4 + r;
            unsigned short* orow = dbuf + (size_t)(base + row) * H_DIM + (size_t)nt * 128 + wn;
#pragma unroll
            for (int j = 0; j < 4; j++)
                orow[j * 16 + l16] = f2bf(acc[i][j][r]);
        }
    }
}

// ---------- combine: out[t] = dbuf[slot0] + dbuf[slot1] (bf16 in, fp32 out) ----------
__global__ __launch_bounds__(256)
void combine_kernel(const unsigned short* __restrict__ dbuf, const int* __restrict__ slot_of,
                    float* __restrict__ out) {
    int t = blockIdx.x;
    int s0 = slot_of[2 * t], s1 = slot_of[2 * t + 1];
    int i = threadIdx.x;   // 256 threads x 4 elems = 1024 = H_DIM
    u16x4 a = *(const u16x4*)(dbuf + (size_t)s0 * H_DIM + i * 4);
    u16x4 b = *(const u16x4*)(dbuf + (size_t)s1 * H_DIM + i * 4);
    f32x4 o;
#pragma unroll
    for (int k = 0; k < 4; k++) o[k] = bf2f(a[k]) + bf2f(b[k]);
    *(f32x4*)(out + (size_t)t * H_DIM + i * 4) = o;
}

extern "C" void kernel_launch(void* const* d_in, const int* in_sizes, int n_in,
                              void* d_out, int out_size, void* d_ws, size_t ws_size,
                              hipStream_t stream) {
    const float* x  = (const float*)d_in[0];
    const float* Wr = (const float*)d_in[1];
    const float* Wg = (const float*)d_in[2];
    const float* Wu = (const float*)d_in[3];
    const float* Wd = (const float*)d_in[4];
    float* out = (float*)d_out;
    char* ws = (char*)d_ws;

    size_t off = 0;
    unsigned short* xb   = (unsigned short*)(ws + off); off += (size_t)T_TOK * H_DIM * 2;
    unsigned short* wgT  = (unsigned short*)(ws + off); off += (size_t)E_NUM * H_DIM * I_DIM * 2;
    unsigned short* wuT  = (unsigned short*)(ws + off); off += (size_t)E_NUM * H_DIM * I_DIM * 2;
    unsigned short* wdT  = (unsigned short*)(ws + off); off += (size_t)E_NUM * H_DIM * I_DIM * 2;
    unsigned short* hbuf = (unsigned short*)(ws + off); off += (size_t)CAP * I_DIM * 2;
    unsigned short* dbuf = (unsigned short*)(ws + off); off += (size_t)CAP * H_DIM * 2;
    int*   topidx  = (int*)(ws + off);   off += (size_t)T_TOK * 2 * 4;
    float* topw    = (float*)(ws + off); off += (size_t)T_TOK * 2 * 4;
    int*   slot_of = (int*)(ws + off);   off += (size_t)T_TOK * 2 * 4;
    int*   meta    = (int*)(ws + off);   off += 1024;
    int*   ntiles  = meta + 33;     // 1
    int*   tile_e  = meta + 64;     // 72
    int*   tile_b  = meta + 136;    // 72
    int*   list_tok = (int*)(ws + off);  off += (size_t)CAP * 4;
    float* list_w   = (float*)(ws + off); off += (size_t)CAP * 4;

    router_kernel<<<T_TOK / 4, 256, 0, stream>>>(x, Wr, xb, topidx, topw);
    transpose_all<<<dim3(32, 16, 24), 256, 0, stream>>>(Wg, Wu, Wd, wgT, wuT, wdT);
    offsets_scatter_kernel<<<1, 256, 0, stream>>>(topidx, topw, tile_e, tile_b, ntiles, list_tok, list_w, slot_of);
    gemm_gateup<<<dim3(MAXTILES, I_DIM / 64), 256, 0, stream>>>(xb, wgT, wuT, list_tok, list_w, tile_e, tile_b, ntiles, hbuf);
    gemm_down<<<dim3(MAXTILES, H_DIM / 128), 256, 0, stream>>>(hbuf, wdT, tile_e, tile_b, ntiles, dbuf);
    combine_kernel<<<T_TOK, 256, 0, stream>>>(dbuf, slot_of, out);
}